// Round 6
// baseline (1177.392 us; speedup 1.0000x reference)
//
#include <hip/hip_runtime.h>
#include <hip/hip_bf16.h>

typedef __attribute__((ext_vector_type(8))) short short8;
typedef __attribute__((ext_vector_type(4))) float f32x4;

#define NT 32
#define NB 64
#define NA 16
#define NF 128
#define DT 512
#define NH 8
#define NHD 64

__device__ __forceinline__ unsigned short f2b(float f) {
  union { float f; unsigned u; } c; c.f = f;
  unsigned r = c.u + 0x7fffu + ((c.u >> 16) & 1u);
  return (unsigned short)(r >> 16);
}
__device__ __forceinline__ float b2f(unsigned short u) {
  union { unsigned u; float f; } c; c.u = ((unsigned)u) << 16;
  return c.f;
}
// packed f32x2 -> bf16x2 (compiler emits v_cvt_pk_bf16_f32; RNE like f2b)
__device__ __forceinline__ unsigned cvt2(float a, float b) {
  return (unsigned)__bfloat16_as_ushort(__float2bfloat16(a)) |
         ((unsigned)__bfloat16_as_ushort(__float2bfloat16(b)) << 16);
}

__device__ __forceinline__ void gload16(const void* g, void* l) {
  __builtin_amdgcn_global_load_lds(
      (const __attribute__((address_space(1))) void*)g,
      (__attribute__((address_space(3))) void*)l, 16, 0, 0);
}

// ---------------- weight cast: f32 -> bf16, 8 elems/thread ----------------
__global__ __launch_bounds__(256) void cast_kernel(const float* __restrict__ src,
                                                   unsigned short* __restrict__ dst) {
  long i = ((long)blockIdx.x * 256 + threadIdx.x) * 8;
  float4 v0 = *(const float4*)(src + i);
  float4 v1 = *(const float4*)(src + i + 4);
  uint4 o;
  o.x = f2b(v0.x) | ((unsigned)f2b(v0.y) << 16);
  o.y = f2b(v0.z) | ((unsigned)f2b(v0.w) << 16);
  o.z = f2b(v1.x) | ((unsigned)f2b(v1.y) << 16);
  o.w = f2b(v1.z) | ((unsigned)f2b(v1.w) << 16);
  *(uint4*)(dst + i) = o;
}

// =============== m97-structure 128^2 GEMM: C = A(Mx512) @ B(Nx512)^T + bias ===============
// 256 threads = 4 waves (2x2), 4x4 frags, BK=32, 16 KB LDS (multi-block/CU residency).
// B staged via global_load_lds width-16 (linear LDS). A staged per MODE:
//   MODE 0 (KV): A f32 -> reg -> cvt_pk bf16 -> LDS  (fused cast; no ctx prepass)
//   MODE 1 (Q) : A f32 -> same fused cast
//   MODE 2 (O) : A bf16 -> global_load_lds
// 1D grid, XCD-bijective swizzle, colTile in low CBITS bits (A fetched once per XCD set).
template <int MODE, int CBITS>
__global__ __launch_bounds__(256) void gemm_lds(const void* __restrict__ A_,
                                                const unsigned short* __restrict__ Bg,
                                                const float* __restrict__ bias0,
                                                const float* __restrict__ bias1,
                                                void* __restrict__ C0_,
                                                void* __restrict__ C1_) {
  __shared__ __align__(16) unsigned short As[128 * 32];
  __shared__ __align__(16) unsigned short Bs[128 * 32];
  const int tid = threadIdx.x;
  const int lane = tid & 63;
  const int l4 = lane & 15, lg = lane >> 4;
  const int w = tid >> 6;
  const int wm = w >> 1, wn = w & 1;

  const int nwg = gridDim.x;
  const int bid = blockIdx.x;
  const int swz = (bid & 7) * (nwg >> 3) + (bid >> 3);
  const long rowTile = swz >> CBITS;
  const int colTile = swz & ((1 << CBITS) - 1);

  // B staging (glds): lane covers row lane>>2, 16B col (lane&3)*8; wave w rows w*16, +64
  const int srow = lane >> 2;
  const int scol = (lane & 3) * 8;
  const unsigned short* Bb = Bg + ((long)colTile * 128 + w * 16 + srow) * 512L + scol;
  const unsigned short* Bb2 = Bb + 64 * 512L;
  unsigned short* lB = Bs + w * 512;
  unsigned short* lB2 = Bs + (w + 4) * 512;

  // A staging (MODE 0/1): thread covers row tid>>1, 16 f32 cols at (tid&1)*16
  const int arow = tid >> 1;
  const int acol = (tid & 1) * 16;
  const float* Af = (const float*)A_ + (rowTile * 128 + arow) * 512L + acol;
  // A staging (MODE 2): glds, same geometry as B
  const unsigned short* Ab = (const unsigned short*)A_ + (rowTile * 128 + w * 16 + srow) * 512L + scol;
  const unsigned short* Ab2 = Ab + 64 * 512L;
  unsigned short* lA = As + w * 512;
  unsigned short* lA2 = As + (w + 4) * 512;

  const f32x4 zero = {0.f, 0.f, 0.f, 0.f};
  f32x4 acc[4][4];
#pragma unroll
  for (int i = 0; i < 4; i++)
#pragma unroll
    for (int j = 0; j < 4; j++) acc[i][j] = zero;

  for (int k0 = 0; k0 < 512; k0 += 32) {
    if constexpr (MODE == 2) {
      gload16(Ab + k0, lA);
      gload16(Ab2 + k0, lA2);
      gload16(Bb + k0, lB);
      gload16(Bb2 + k0, lB2);
    } else {
      // issue f32 A loads, then B glds, then cvt+LDS-store (overlaps with B in flight)
      float4 v0 = *(const float4*)(Af + k0);
      float4 v1 = *(const float4*)(Af + k0 + 4);
      float4 v2 = *(const float4*)(Af + k0 + 8);
      float4 v3 = *(const float4*)(Af + k0 + 12);
      gload16(Bb + k0, lB);
      gload16(Bb2 + k0, lB2);
      uint4 o0;
      o0.x = cvt2(v0.x, v0.y);
      o0.y = cvt2(v0.z, v0.w);
      o0.z = cvt2(v1.x, v1.y);
      o0.w = cvt2(v1.z, v1.w);
      uint4 o1;
      o1.x = cvt2(v2.x, v2.y);
      o1.y = cvt2(v2.z, v2.w);
      o1.z = cvt2(v3.x, v3.y);
      o1.w = cvt2(v3.z, v3.w);
      *(uint4*)&As[arow * 32 + acol] = o0;
      *(uint4*)&As[arow * 32 + acol + 8] = o1;
    }
    __syncthreads();
    short8 af[4], bfr[4];
#pragma unroll
    for (int i = 0; i < 4; i++)
      af[i] = *(const short8*)(As + (wm * 64 + i * 16 + l4) * 32 + lg * 8);
#pragma unroll
    for (int j = 0; j < 4; j++)
      bfr[j] = *(const short8*)(Bs + (wn * 64 + j * 16 + l4) * 32 + lg * 8);
#pragma unroll
    for (int i = 0; i < 4; i++)
#pragma unroll
      for (int j = 0; j < 4; j++)
        acc[i][j] = __builtin_amdgcn_mfma_f32_16x16x32_bf16(af[i], bfr[j], acc[i][j], 0, 0, 0);
    __syncthreads();
  }

  const long rowBase = rowTile * 128 + wm * 64;

  if constexpr (MODE == 0) {  // KV
    if (colTile < 4) {        // K side: row-linear ((t,f,b) reshape is a memory no-op)
      unsigned short* C = (unsigned short*)C0_;
#pragma unroll
      for (int j = 0; j < 4; j++) {
        int gCol = colTile * 128 + wn * 64 + j * 16 + l4;
        float bs = bias0[gCol];
#pragma unroll
        for (int i = 0; i < 4; i++)
#pragma unroll
          for (int r = 0; r < 4; r++) {
            long gRow = rowBase + i * 16 + lg * 4 + r;
            C[gRow * 512 + gCol] = f2b(acc[i][j][r] + bs);
          }
      }
    } else {  // V side: row (fi*64+bi) -> (bi*128+fi) within each t
      unsigned short* C = (unsigned short*)C1_;
#pragma unroll
      for (int j = 0; j < 4; j++) {
        int gCol = colTile * 128 + wn * 64 + j * 16 + l4 - 512;
        float bs = bias1[gCol];
#pragma unroll
        for (int i = 0; i < 4; i++)
#pragma unroll
          for (int r = 0; r < 4; r++) {
            long gRow = rowBase + i * 16 + lg * 4 + r;
            long rr = gRow & 8191;
            long vrow = (gRow - rr) + ((rr & 63) << 7) + (rr >> 6);
            C[vrow * 512 + gCol] = f2b(acc[i][j][r] + bs);
          }
      }
    }
  } else if constexpr (MODE == 1) {  // Q: bf16 row-linear
    unsigned short* C = (unsigned short*)C0_;
#pragma unroll
    for (int j = 0; j < 4; j++) {
      int gCol = colTile * 128 + wn * 64 + j * 16 + l4;
      float bs = bias0[gCol];
#pragma unroll
      for (int i = 0; i < 4; i++)
#pragma unroll
        for (int r = 0; r < 4; r++) {
          long gRow = rowBase + i * 16 + lg * 4 + r;
          C[gRow * 512 + gCol] = f2b(acc[i][j][r] + bs);
        }
    }
  } else {  // O: f32, rows (t*64+b)*16+a -> out row (t*16+a)*64+b
    float* C = (float*)C0_;
#pragma unroll
    for (int j = 0; j < 4; j++) {
      int gCol = colTile * 128 + wn * 64 + j * 16 + l4;
      float bs = bias0[gCol];
#pragma unroll
      for (int i = 0; i < 4; i++)
#pragma unroll
        for (int r = 0; r < 4; r++) {
          long gRow = rowBase + i * 16 + lg * 4 + r;
          long tt = gRow >> 10;
          long bi = (gRow >> 4) & 63;
          long ai = gRow & 15;
          long orow = ((tt * 16 + ai) << 6) + bi;
          C[orow * 512 + gCol] = acc[i][j][r] + bs;
        }
    }
  }
}

// ---------------- attention: one block per (t,b); 4 waves x 2 heads ----------------
__global__ __launch_bounds__(256, 2) void attn_kernel(const unsigned short* __restrict__ Kst,
                                                      const unsigned short* __restrict__ Vst,
                                                      const unsigned short* __restrict__ Qst,
                                                      const int* __restrict__ mask,
                                                      float* __restrict__ wout,
                                                      unsigned short* __restrict__ attn_out) {
  __shared__ float wsh[4][NF * NA];
  __shared__ int msh[NF];
  const int tid = threadIdx.x;
  const int lane = tid & 63;
  const int l4 = lane & 15, lg = lane >> 4;
  const int w = tid >> 6;
  const int tb = blockIdx.x;
  const int b = tb & 63;
  if (tid < NF) msh[tid] = mask[b * NF + tid];
  __syncthreads();

  const unsigned short* Kbase = Kst + (long)tb * NF * DT;
  const unsigned short* Vbase = Vst + (long)tb * NF * DT;
  const unsigned short* Qbase = Qst + (long)tb * NA * DT;
  const f32x4 zero = {0.f, 0.f, 0.f, 0.f};

  for (int hh = 0; hh < 2; hh++) {
    const int h = w * 2 + hh;
    const int co = h * 64;
    f32x4 acc[8];
#pragma unroll
    for (int i = 0; i < 8; i++) acc[i] = zero;
#pragma unroll
    for (int ks = 0; ks < 2; ks++) {
      short8 qf = *(const short8*)(Qbase + (long)l4 * DT + co + ks * 32 + lg * 8);
#pragma unroll
      for (int m0 = 0; m0 < 8; m0++) {
        short8 kf = *(const short8*)(Kbase + (long)(m0 * 16 + l4) * DT + co + ks * 32 + lg * 8);
        acc[m0] = __builtin_amdgcn_mfma_f32_16x16x32_bf16(kf, qf, acc[m0], 0, 0, 0);
      }
    }
    float lv[8][4];
    float mx = -3.0e38f;
#pragma unroll
    for (int m0 = 0; m0 < 8; m0++)
#pragma unroll
      for (int r = 0; r < 4; r++) {
        int f = m0 * 16 + lg * 4 + r;
        float v = acc[m0][r] * 0.125f;
        if (msh[f] == 0) v = -1.0e9f;
        lv[m0][r] = v;
        mx = fmaxf(mx, v);
      }
    mx = fmaxf(mx, __shfl_xor(mx, 16, 64));
    mx = fmaxf(mx, __shfl_xor(mx, 32, 64));
    float s = 0.f;
#pragma unroll
    for (int m0 = 0; m0 < 8; m0++)
#pragma unroll
      for (int r = 0; r < 4; r++) {
        float p = __expf(lv[m0][r] - mx);
        lv[m0][r] = p;
        s += p;
      }
    s += __shfl_xor(s, 16, 64);
    s += __shfl_xor(s, 32, 64);
    float inv = 1.0f / s;
    float* wrow = wout + ((long)tb * NH + h) * (NF * NA);
#pragma unroll
    for (int m0 = 0; m0 < 8; m0++)
#pragma unroll
      for (int r = 0; r < 4; r++) {
        int f = m0 * 16 + lg * 4 + r;
        float wv = lv[m0][r] * inv;
        wsh[w][f * 16 + l4] = wv;
        wrow[f * 16 + l4] = wv;
      }
    float pv[16];
#pragma unroll
    for (int a = 0; a < 16; a++) pv[a] = 0.f;
#pragma unroll 4
    for (int f = 0; f < NF; f++) {
      float vv = b2f(Vbase[(long)f * DT + co + lane]);
      const float4* wp = (const float4*)&wsh[w][f * 16];
      float4 w0 = wp[0], w1 = wp[1], w2 = wp[2], w3 = wp[3];
      pv[0] += vv * w0.x;  pv[1] += vv * w0.y;  pv[2] += vv * w0.z;  pv[3] += vv * w0.w;
      pv[4] += vv * w1.x;  pv[5] += vv * w1.y;  pv[6] += vv * w1.z;  pv[7] += vv * w1.w;
      pv[8] += vv * w2.x;  pv[9] += vv * w2.y;  pv[10] += vv * w2.z; pv[11] += vv * w2.w;
      pv[12] += vv * w3.x; pv[13] += vv * w3.y; pv[14] += vv * w3.z; pv[15] += vv * w3.w;
    }
#pragma unroll
    for (int a = 0; a < 16; a++)
      attn_out[((long)tb * NA + a) * DT + co + lane] = f2b(pv[a]);
  }
}

extern "C" void kernel_launch(void* const* d_in, const int* in_sizes, int n_in,
                              void* d_out, int out_size, void* d_ws, size_t ws_size,
                              hipStream_t stream) {
  const float* q_embeds = (const float*)d_in[0];
  const float* ctx = (const float*)d_in[1];
  const int* mask = (const int*)d_in[2];
  const float* Wq = (const float*)d_in[3];
  const float* bq = (const float*)d_in[4];
  const float* Wk = (const float*)d_in[5];
  const float* bk = (const float*)d_in[6];
  const float* Wv = (const float*)d_in[7];
  const float* bv = (const float*)d_in[8];
  const float* Wo = (const float*)d_in[9];
  const float* bo = (const float*)d_in[10];

  float* out0 = (float*)d_out;                   // (t,a,b,d) f32
  float* wout = out0 + (long)NT * NA * NB * DT;  // (t,b,H,f,a) f32

  // workspace (bf16 as ushort) — r1 footprint (606 MB, known to fit)
  const long W_ELEMS = 4L * 512 * 512;
  const long MQ = (long)NT * NB * NA;    // 32768
  const long MKV = (long)NT * NF * NB;   // 262144
  unsigned short* Wb = (unsigned short*)d_ws;
  unsigned short* Qst = Wb + W_ELEMS;
  unsigned short* Kst = Qst + MQ * DT;
  unsigned short* Vst = Kst + MKV * DT;
  unsigned short* attnst = Vst + MKV * DT;
  size_t needed = (size_t)(W_ELEMS + 2 * MQ * DT + 2 * MKV * DT) * 2;
  if (ws_size < needed) return;

  cast_kernel<<<128, 256, 0, stream>>>(Wq, Wb);
  cast_kernel<<<128, 256, 0, stream>>>(Wk, Wb + 512 * 512);
  cast_kernel<<<128, 256, 0, stream>>>(Wv, Wb + 2 * 512 * 512);
  cast_kernel<<<128, 256, 0, stream>>>(Wo, Wb + 3 * 512 * 512);

  // Q projection: f32 A fused-cast in staging
  gemm_lds<1, 2><<<(unsigned)(MQ / 128 * 4), 256, 0, stream>>>(
      q_embeds, Wb, bq, nullptr, Qst, nullptr);

  // K+V projection: f32 ctx A fused-cast in staging, single launch (no prepass)
  gemm_lds<0, 3><<<(unsigned)(MKV / 128 * 8), 256, 0, stream>>>(
      ctx, Wb + 512 * 512, bk, bv, Kst, Vst);

  attn_kernel<<<NT * NB, 256, 0, stream>>>(Kst, Vst, Qst, mask, wout, attnst);

  gemm_lds<2, 2><<<(unsigned)(MQ / 128 * 4), 256, 0, stream>>>(
      attnst, Wb + 3 * 512 * 512, bo, nullptr, out0, nullptr);
}

// Round 7
// 901.249 us; speedup vs baseline: 1.3064x; 1.3064x over previous
//
#include <hip/hip_runtime.h>

typedef __attribute__((ext_vector_type(8))) short short8;
typedef __attribute__((ext_vector_type(4))) float f32x4;

#define NT 32
#define NB 64
#define NA 16
#define NF 128
#define DT 512
#define NH 8
#define NHD 64

__device__ __forceinline__ unsigned short f2b(float f) {
  union { float f; unsigned u; } c; c.f = f;
  unsigned r = c.u + 0x7fffu + ((c.u >> 16) & 1u);
  return (unsigned short)(r >> 16);
}
__device__ __forceinline__ float b2f(unsigned short u) {
  union { unsigned u; float f; } c; c.u = ((unsigned)u) << 16;
  return c.f;
}

__device__ __forceinline__ void gload16(const void* g, void* l) {
  __builtin_amdgcn_global_load_lds(
      (const __attribute__((address_space(1))) void*)g,
      (__attribute__((address_space(3))) void*)l, 16, 0, 0);
}

#define BAR() asm volatile("s_barrier" ::: "memory")

// ---------------- f32 -> bf16 cast, 8 elems/thread ----------------
__global__ __launch_bounds__(256) void cast_kernel(const float* __restrict__ src,
                                                   unsigned short* __restrict__ dst) {
  long i = ((long)blockIdx.x * 256 + threadIdx.x) * 8;
  float4 v0 = *(const float4*)(src + i);
  float4 v1 = *(const float4*)(src + i + 4);
  uint4 o;
  o.x = f2b(v0.x) | ((unsigned)f2b(v0.y) << 16);
  o.y = f2b(v0.z) | ((unsigned)f2b(v0.w) << 16);
  o.z = f2b(v1.x) | ((unsigned)f2b(v1.y) << 16);
  o.w = f2b(v1.z) | ((unsigned)f2b(v1.w) << 16);
  *(uint4*)(dst + i) = o;
}

// =============== 256x256 deep-pipelined GEMM (r4, proven): C = A@B^T + bias ===============
#define AFRAG(S, M, KS) \
  (*(const short8*)&As[S][(wm * 128 + (M)*16 + l4) * 64 + ((((KS)*32) + lg * 8) ^ ((l4 & 7) << 3))])
#define BFRAG(S, N, KS) \
  (*(const short8*)&Bs[S][(wn * 64 + (N)*16 + l4) * 64 + ((((KS)*32) + lg * 8) ^ ((l4 & 7) << 3))])

template <int MODE, int NCB>  // MODE 0 = KV
__global__ __launch_bounds__(512, 2) void gemm256(const unsigned short* __restrict__ A,
                                                  const unsigned short* __restrict__ Bg,
                                                  const float* __restrict__ bias0,
                                                  const float* __restrict__ bias1,
                                                  void* __restrict__ C0_,
                                                  void* __restrict__ C1_,
                                                  long row0) {
  __shared__ __align__(16) unsigned short As[2][256 * 64];
  __shared__ __align__(16) unsigned short Bs[2][256 * 64];
  const int tid = threadIdx.x;
  const int lane = tid & 63;
  const int l4 = lane & 15, lg = lane >> 4;
  const int w = tid >> 6;
  const int wm = w >> 2, wn = w & 3;

  const int nwg = gridDim.x;
  const int bid = blockIdx.x;
  const int swz = (bid & 7) * (nwg >> 3) + (bid >> 3);
  const long rowTile = swz >> NCB;
  const int colTile = swz & ((1 << NCB) - 1);

  const int r_d = tid >> 3;
  const int c_sw = ((tid & 7) << 4) ^ ((r_d & 7) << 4);
  const unsigned short* Agl = A + (rowTile * 256 + r_d) * 512L + (c_sw >> 1);
  const unsigned short* Bgl = Bg + ((long)colTile * 256 + r_d) * 512L + (c_sw >> 1);

  auto stage = [&](int s, int kc) {
    const unsigned short* ga = Agl + kc;
    const unsigned short* gb = Bgl + kc;
    gload16(ga, &As[s][w * 512]);
    gload16(ga + 64 * 512, &As[s][4096 + w * 512]);
    gload16(ga + 128 * 512, &As[s][8192 + w * 512]);
    gload16(ga + 192 * 512, &As[s][12288 + w * 512]);
    gload16(gb, &Bs[s][w * 512]);
    gload16(gb + 64 * 512, &Bs[s][4096 + w * 512]);
    gload16(gb + 128 * 512, &Bs[s][8192 + w * 512]);
    gload16(gb + 192 * 512, &Bs[s][12288 + w * 512]);
  };

  const f32x4 zero = {0.f, 0.f, 0.f, 0.f};
  f32x4 acc[8][4];
#pragma unroll
  for (int i = 0; i < 8; i++)
#pragma unroll
    for (int j = 0; j < 4; j++) acc[i][j] = zero;

  stage(0, 0);

#pragma unroll 1
  for (int g = 0; g < 8; g++) {
    const int s = g & 1;
    BAR();
    if (g < 7) {
      stage(s ^ 1, (g + 1) * 64);
      asm volatile("s_waitcnt vmcnt(8)" ::: "memory");
    } else {
      asm volatile("s_waitcnt vmcnt(0)" ::: "memory");
    }
    BAR();
#pragma unroll
    for (int ks = 0; ks < 2; ks++) {
      short8 b0 = BFRAG(s, 0, ks);
      short8 b1 = BFRAG(s, 1, ks);
      short8 b2 = BFRAG(s, 2, ks);
      short8 b3 = BFRAG(s, 3, ks);
#pragma unroll
      for (int mh = 0; mh < 2; mh++) {
        short8 a0 = AFRAG(s, mh * 4 + 0, ks);
        short8 a1 = AFRAG(s, mh * 4 + 1, ks);
        short8 a2 = AFRAG(s, mh * 4 + 2, ks);
        short8 a3 = AFRAG(s, mh * 4 + 3, ks);
        __builtin_amdgcn_s_setprio(1);
        acc[mh * 4 + 0][0] = __builtin_amdgcn_mfma_f32_16x16x32_bf16(a0, b0, acc[mh * 4 + 0][0], 0, 0, 0);
        acc[mh * 4 + 0][1] = __builtin_amdgcn_mfma_f32_16x16x32_bf16(a0, b1, acc[mh * 4 + 0][1], 0, 0, 0);
        acc[mh * 4 + 0][2] = __builtin_amdgcn_mfma_f32_16x16x32_bf16(a0, b2, acc[mh * 4 + 0][2], 0, 0, 0);
        acc[mh * 4 + 0][3] = __builtin_amdgcn_mfma_f32_16x16x32_bf16(a0, b3, acc[mh * 4 + 0][3], 0, 0, 0);
        acc[mh * 4 + 1][0] = __builtin_amdgcn_mfma_f32_16x16x32_bf16(a1, b0, acc[mh * 4 + 1][0], 0, 0, 0);
        acc[mh * 4 + 1][1] = __builtin_amdgcn_mfma_f32_16x16x32_bf16(a1, b1, acc[mh * 4 + 1][1], 0, 0, 0);
        acc[mh * 4 + 1][2] = __builtin_amdgcn_mfma_f32_16x16x32_bf16(a1, b2, acc[mh * 4 + 1][2], 0, 0, 0);
        acc[mh * 4 + 1][3] = __builtin_amdgcn_mfma_f32_16x16x32_bf16(a1, b3, acc[mh * 4 + 1][3], 0, 0, 0);
        acc[mh * 4 + 2][0] = __builtin_amdgcn_mfma_f32_16x16x32_bf16(a2, b0, acc[mh * 4 + 2][0], 0, 0, 0);
        acc[mh * 4 + 2][1] = __builtin_amdgcn_mfma_f32_16x16x32_bf16(a2, b1, acc[mh * 4 + 2][1], 0, 0, 0);
        acc[mh * 4 + 2][2] = __builtin_amdgcn_mfma_f32_16x16x32_bf16(a2, b2, acc[mh * 4 + 2][2], 0, 0, 0);
        acc[mh * 4 + 2][3] = __builtin_amdgcn_mfma_f32_16x16x32_bf16(a2, b3, acc[mh * 4 + 2][3], 0, 0, 0);
        acc[mh * 4 + 3][0] = __builtin_amdgcn_mfma_f32_16x16x32_bf16(a3, b0, acc[mh * 4 + 3][0], 0, 0, 0);
        acc[mh * 4 + 3][1] = __builtin_amdgcn_mfma_f32_16x16x32_bf16(a3, b1, acc[mh * 4 + 3][1], 0, 0, 0);
        acc[mh * 4 + 3][2] = __builtin_amdgcn_mfma_f32_16x16x32_bf16(a3, b2, acc[mh * 4 + 3][2], 0, 0, 0);
        acc[mh * 4 + 3][3] = __builtin_amdgcn_mfma_f32_16x16x32_bf16(a3, b3, acc[mh * 4 + 3][3], 0, 0, 0);
        __builtin_amdgcn_s_setprio(0);
      }
    }
  }

  const long gRowBase = row0 + rowTile * 256 + wm * 128;

  if constexpr (MODE == 0) {
    if (colTile < 2) {  // K side: row-linear
      unsigned short* C = (unsigned short*)C0_;
#pragma unroll
      for (int n = 0; n < 4; n++) {
        int gCol = colTile * 256 + wn * 64 + n * 16 + l4;
        float bs = bias0[gCol];
#pragma unroll
        for (int m = 0; m < 8; m++)
#pragma unroll
          for (int r = 0; r < 4; r++) {
            long gRow = gRowBase + m * 16 + lg * 4 + r;
            C[gRow * 512 + gCol] = f2b(acc[m][n][r] + bs);
          }
      }
    } else {  // V side: row (fi*64+bi) -> (bi*128+fi) within each t
      unsigned short* C = (unsigned short*)C1_;
#pragma unroll
      for (int n = 0; n < 4; n++) {
        int gCol = (colTile - 2) * 256 + wn * 64 + n * 16 + l4;
        float bs = bias1[gCol];
#pragma unroll
        for (int m = 0; m < 8; m++)
#pragma unroll
          for (int r = 0; r < 4; r++) {
            long gRow = gRowBase + m * 16 + lg * 4 + r;
            long rr = gRow & 8191;
            long vrow = (gRow - rr) + ((rr & 63) << 7) + (rr >> 6);
            C[vrow * 512 + gCol] = f2b(acc[m][n][r] + bs);
          }
      }
    }
  }
}

// ---------------- Q projection (r2, proven): f32 A, cvt in staging, pitch-40 LDS ----------------
__global__ __launch_bounds__(256, 2) void gemm_q(const float* __restrict__ Ag,
                                                 const unsigned short* __restrict__ Bg,
                                                 const float* __restrict__ bias0,
                                                 unsigned short* __restrict__ C) {
  __shared__ unsigned short As[128][40];
  __shared__ unsigned short Bs[128][40];
  const int tid = threadIdx.x;
  const int lane = tid & 63;
  const int l4 = lane & 15, lg = lane >> 4;
  const int w = tid >> 6;
  const int wm = w >> 1, wn = w & 1;
  const long rowTile = blockIdx.x;
  const int colTile = blockIdx.y;
  const int srow = tid >> 1;
  const int scol = (tid & 1) * 16;

  const f32x4 zero = {0.f, 0.f, 0.f, 0.f};
  f32x4 acc[4][4];
#pragma unroll
  for (int i = 0; i < 4; i++)
#pragma unroll
    for (int j = 0; j < 4; j++) acc[i][j] = zero;

  for (int k0 = 0; k0 < 512; k0 += 32) {
    {
      const uint4* src = (const uint4*)(Bg + (long)(colTile * 128 + srow) * 512 + k0 + scol);
      uint4 b0 = src[0], b1 = src[1];
      *(uint4*)&Bs[srow][scol] = b0;
      *(uint4*)&Bs[srow][scol + 8] = b1;
    }
    {
      const float4* src = (const float4*)(Ag + (rowTile * 128 + srow) * 512 + k0 + scol);
      float4 v0 = src[0], v1 = src[1], v2 = src[2], v3 = src[3];
      uint4 o0, o1;
      o0.x = f2b(v0.x) | ((unsigned)f2b(v0.y) << 16);
      o0.y = f2b(v0.z) | ((unsigned)f2b(v0.w) << 16);
      o0.z = f2b(v1.x) | ((unsigned)f2b(v1.y) << 16);
      o0.w = f2b(v1.z) | ((unsigned)f2b(v1.w) << 16);
      o1.x = f2b(v2.x) | ((unsigned)f2b(v2.y) << 16);
      o1.y = f2b(v2.z) | ((unsigned)f2b(v2.w) << 16);
      o1.z = f2b(v3.x) | ((unsigned)f2b(v3.y) << 16);
      o1.w = f2b(v3.z) | ((unsigned)f2b(v3.w) << 16);
      *(uint4*)&As[srow][scol] = o0;
      *(uint4*)&As[srow][scol + 8] = o1;
    }
    __syncthreads();
    short8 af[4], bfv[4];
#pragma unroll
    for (int i = 0; i < 4; i++) af[i] = *(const short8*)&As[wm * 64 + i * 16 + l4][lg * 8];
#pragma unroll
    for (int i = 0; i < 4; i++) bfv[i] = *(const short8*)&Bs[wn * 64 + i * 16 + l4][lg * 8];
#pragma unroll
    for (int i = 0; i < 4; i++)
#pragma unroll
      for (int j = 0; j < 4; j++)
        acc[i][j] = __builtin_amdgcn_mfma_f32_16x16x32_bf16(af[i], bfv[j], acc[i][j], 0, 0, 0);
    __syncthreads();
  }

  const long rowBase = rowTile * 128 + wm * 64;
#pragma unroll
  for (int j = 0; j < 4; j++) {
    int gCol = colTile * 128 + wn * 64 + j * 16 + l4;
    float bs = bias0[gCol];
#pragma unroll
    for (int i = 0; i < 4; i++)
#pragma unroll
      for (int r = 0; r < 4; r++) {
        long gRow = rowBase + i * 16 + lg * 4 + r;
        C[gRow * 512 + gCol] = f2b(acc[i][j][r] + bs);
      }
  }
}

// ---------------- O projection (r6 MODE-2, proven): glds bf16 A/B, 128^2, f32 out ----------------
__global__ __launch_bounds__(256) void gemm_o(const unsigned short* __restrict__ A,
                                              const unsigned short* __restrict__ Bg,
                                              const float* __restrict__ bias0,
                                              float* __restrict__ C) {
  __shared__ __align__(16) unsigned short As[128 * 32];
  __shared__ __align__(16) unsigned short Bs[128 * 32];
  const int tid = threadIdx.x;
  const int lane = tid & 63;
  const int l4 = lane & 15, lg = lane >> 4;
  const int w = tid >> 6;
  const int wm = w >> 1, wn = w & 1;

  const int nwg = gridDim.x;
  const int bid = blockIdx.x;
  const int swz = (bid & 7) * (nwg >> 3) + (bid >> 3);
  const long rowTile = swz >> 2;
  const int colTile = swz & 3;

  const int srow = lane >> 2;
  const int scol = (lane & 3) * 8;
  const unsigned short* Ab = A + (rowTile * 128 + w * 16 + srow) * 512L + scol;
  const unsigned short* Ab2 = Ab + 64 * 512L;
  const unsigned short* Bb = Bg + ((long)colTile * 128 + w * 16 + srow) * 512L + scol;
  const unsigned short* Bb2 = Bb + 64 * 512L;
  unsigned short* lA = As + w * 512;
  unsigned short* lA2 = As + (w + 4) * 512;
  unsigned short* lB = Bs + w * 512;
  unsigned short* lB2 = Bs + (w + 4) * 512;

  const f32x4 zero = {0.f, 0.f, 0.f, 0.f};
  f32x4 acc[4][4];
#pragma unroll
  for (int i = 0; i < 4; i++)
#pragma unroll
    for (int j = 0; j < 4; j++) acc[i][j] = zero;

  for (int k0 = 0; k0 < 512; k0 += 32) {
    gload16(Ab + k0, lA);
    gload16(Ab2 + k0, lA2);
    gload16(Bb + k0, lB);
    gload16(Bb2 + k0, lB2);
    __syncthreads();
    short8 af[4], bfr[4];
#pragma unroll
    for (int i = 0; i < 4; i++)
      af[i] = *(const short8*)(As + (wm * 64 + i * 16 + l4) * 32 + lg * 8);
#pragma unroll
    for (int j = 0; j < 4; j++)
      bfr[j] = *(const short8*)(Bs + (wn * 64 + j * 16 + l4) * 32 + lg * 8);
#pragma unroll
    for (int i = 0; i < 4; i++)
#pragma unroll
      for (int j = 0; j < 4; j++)
        acc[i][j] = __builtin_amdgcn_mfma_f32_16x16x32_bf16(af[i], bfr[j], acc[i][j], 0, 0, 0);
    __syncthreads();
  }

  const long rowBase = rowTile * 128 + wm * 64;
#pragma unroll
  for (int j = 0; j < 4; j++) {
    int gCol = colTile * 128 + wn * 64 + j * 16 + l4;
    float bs = bias0[gCol];
#pragma unroll
    for (int i = 0; i < 4; i++)
#pragma unroll
      for (int r = 0; r < 4; r++) {
        long gRow = rowBase + i * 16 + lg * 4 + r;
        long tt = gRow >> 10;
        long bi = (gRow >> 4) & 63;
        long ai = gRow & 15;
        long orow = ((tt * 16 + ai) << 6) + bi;
        C[orow * 512 + gCol] = acc[i][j][r] + bs;
      }
  }
}

// ---------------- attention: one block per (t,b); 4 waves x 2 heads; MFMA PV ----------------
__global__ __launch_bounds__(256) void attn_kernel(const unsigned short* __restrict__ Kst,
                                                   const unsigned short* __restrict__ Vst,
                                                   const unsigned short* __restrict__ Qst,
                                                   const int* __restrict__ mask,
                                                   float* __restrict__ wout,
                                                   unsigned short* __restrict__ attn_out) {
  __shared__ __align__(16) unsigned short wt[4][16][136];  // per-wave W^T bf16 [a][f], pad 136
  __shared__ int msh[NF];
  const int tid = threadIdx.x;
  const int lane = tid & 63;
  const int l4 = lane & 15, lg = lane >> 4;
  const int w = tid >> 6;
  const int tb = blockIdx.x;
  const int b = tb & 63;
  if (tid < NF) msh[tid] = mask[b * NF + tid];
  __syncthreads();

  const unsigned short* Kbase = Kst + (long)tb * NF * DT;
  const unsigned short* Vbase = Vst + (long)tb * NF * DT;
  const unsigned short* Qbase = Qst + (long)tb * NA * DT;
  const f32x4 zero = {0.f, 0.f, 0.f, 0.f};

  for (int hh = 0; hh < 2; hh++) {
    const int h = w * 2 + hh;
    const int co = h * 64;
    // ---- QK^T: logits[f][a], 16 MFMA ----
    f32x4 acc[8];
#pragma unroll
    for (int i = 0; i < 8; i++) acc[i] = zero;
#pragma unroll
    for (int ks = 0; ks < 2; ks++) {
      short8 qf = *(const short8*)(Qbase + (long)l4 * DT + co + ks * 32 + lg * 8);
#pragma unroll
      for (int m0 = 0; m0 < 8; m0++) {
        short8 kf = *(const short8*)(Kbase + (long)(m0 * 16 + l4) * DT + co + ks * 32 + lg * 8);
        acc[m0] = __builtin_amdgcn_mfma_f32_16x16x32_bf16(kf, qf, acc[m0], 0, 0, 0);
      }
    }
    // ---- softmax over f (rows distributed across lg/regs; a = l4) ----
    float lv[8][4];
    float mx = -3.0e38f;
#pragma unroll
    for (int m0 = 0; m0 < 8; m0++)
#pragma unroll
      for (int r = 0; r < 4; r++) {
        int f = m0 * 16 + lg * 4 + r;
        float v = acc[m0][r] * 0.125f;
        if (msh[f] == 0) v = -1.0e9f;
        lv[m0][r] = v;
        mx = fmaxf(mx, v);
      }
    mx = fmaxf(mx, __shfl_xor(mx, 16, 64));
    mx = fmaxf(mx, __shfl_xor(mx, 32, 64));
    float s = 0.f;
#pragma unroll
    for (int m0 = 0; m0 < 8; m0++)
#pragma unroll
      for (int r = 0; r < 4; r++) {
        float p = __expf(lv[m0][r] - mx);
        lv[m0][r] = p;
        s += p;
      }
    s += __shfl_xor(s, 16, 64);
    s += __shfl_xor(s, 32, 64);
    float inv = 1.0f / s;
    // weights: f32 to wout (output), bf16 transposed [a][f] to LDS for PV B-frags
    float* wrow = wout + ((long)tb * NH + h) * (NF * NA);
#pragma unroll
    for (int m0 = 0; m0 < 8; m0++)
#pragma unroll
      for (int r = 0; r < 4; r++) {
        int f = m0 * 16 + lg * 4 + r;
        float wv = lv[m0][r] * inv;
        wrow[f * 16 + l4] = wv;
        wt[w][l4][f] = f2b(wv);
      }
    asm volatile("s_waitcnt lgkmcnt(0)" ::: "memory");
    __builtin_amdgcn_sched_barrier(0);
    // ---- PV via MFMA: out[hd][a] = sum_f V[f][hd] * w[f][a]; A-frag = V^T (scalar gathers) ----
    f32x4 pacc[4];
#pragma unroll
    for (int m0 = 0; m0 < 4; m0++) pacc[m0] = zero;
#pragma unroll
    for (int ks = 0; ks < 4; ks++) {
      short8 wf = *(const short8*)&wt[w][l4][ks * 32 + lg * 8];
#pragma unroll
      for (int m0 = 0; m0 < 4; m0++) {
        short8 vf;
#pragma unroll
        for (int j = 0; j < 8; j++)
          vf[j] = (short)Vbase[(long)(ks * 32 + lg * 8 + j) * DT + co + m0 * 16 + l4];
        pacc[m0] = __builtin_amdgcn_mfma_f32_16x16x32_bf16(vf, wf, pacc[m0], 0, 0, 0);
      }
    }
    // pacc element: (hd = m0*16 + lg*4 + r, a = l4)
#pragma unroll
    for (int m0 = 0; m0 < 4; m0++)
#pragma unroll
      for (int r = 0; r < 4; r++)
        attn_out[((long)tb * NA + l4) * DT + co + m0 * 16 + lg * 4 + r] = f2b(pacc[m0][r]);
  }
}

extern "C" void kernel_launch(void* const* d_in, const int* in_sizes, int n_in,
                              void* d_out, int out_size, void* d_ws, size_t ws_size,
                              hipStream_t stream) {
  const float* q_embeds = (const float*)d_in[0];
  const float* ctx = (const float*)d_in[1];
  const int* mask = (const int*)d_in[2];
  const float* Wq = (const float*)d_in[3];
  const float* bq = (const float*)d_in[4];
  const float* Wk = (const float*)d_in[5];
  const float* bk = (const float*)d_in[6];
  const float* Wv = (const float*)d_in[7];
  const float* bv = (const float*)d_in[8];
  const float* Wo = (const float*)d_in[9];
  const float* bo = (const float*)d_in[10];

  float* out0 = (float*)d_out;                   // (t,a,b,d) f32
  float* wout = out0 + (long)NT * NA * NB * DT;  // (t,b,H,f,a) f32

  const long W_ELEMS = 4L * 512 * 512;
  const long MQ = (long)NT * NB * NA;    // 32768
  const long MKV = (long)NT * NF * NB;   // 262144
  const long CHUNK_ROWS = MKV / 8;       // 32768
  unsigned short* Wb = (unsigned short*)d_ws;
  unsigned short* Qst = Wb + W_ELEMS;
  unsigned short* Kst = Qst + MQ * DT;
  unsigned short* Vst = Kst + MKV * DT;
  unsigned short* ctxb = Vst + MKV * DT;   // ctx bf16 buffer; dead before attn
  unsigned short* attnst = ctxb;           // alias

  const size_t needed_chunk = (size_t)(W_ELEMS + MQ * DT + 2 * MKV * DT + CHUNK_ROWS * DT) * 2;
  const size_t needed_full = (size_t)(W_ELEMS + MQ * DT + 3 * MKV * DT) * 2;
  if (ws_size < needed_chunk) return;
  const bool fullpass = ws_size >= needed_full;

  cast_kernel<<<128, 256, 0, stream>>>(Wq, Wb);
  cast_kernel<<<128, 256, 0, stream>>>(Wk, Wb + 512 * 512);
  cast_kernel<<<128, 256, 0, stream>>>(Wv, Wb + 2 * 512 * 512);
  cast_kernel<<<128, 256, 0, stream>>>(Wo, Wb + 3 * 512 * 512);

  gemm_q<<<dim3(MQ / 128, 4), 256, 0, stream>>>(q_embeds, Wb, bq, Qst);

  if (fullpass) {
    cast_kernel<<<(unsigned)(MKV * DT / 2048), 256, 0, stream>>>(ctx, ctxb);
    gemm256<0, 2><<<(unsigned)(MKV / 256 * 4), 512, 0, stream>>>(ctxb, Wb + 512 * 512, bk, bv,
                                                                 Kst, Vst, 0);
  } else {
    for (int c = 0; c < 8; c++) {
      cast_kernel<<<(unsigned)(CHUNK_ROWS * DT / 2048), 256, 0, stream>>>(
          ctx + (long)c * CHUNK_ROWS * DT, ctxb);
      gemm256<0, 2><<<(unsigned)(CHUNK_ROWS / 256 * 4), 512, 0, stream>>>(
          ctxb, Wb + 512 * 512, bk, bv, Kst, Vst, (long)c * CHUNK_ROWS);
    }
  }

  attn_kernel<<<NT * NB, 256, 0, stream>>>(Kst, Vst, Qst, mask, wout, attnst);

  gemm_o<<<(unsigned)(MQ / 128 * 4), 256, 0, stream>>>(attnst, Wb + 3 * 512 * 512, bo, out0);
}

// Round 8
// 814.285 us; speedup vs baseline: 1.4459x; 1.1068x over previous
//
#include <hip/hip_runtime.h>

typedef __attribute__((ext_vector_type(8))) short short8;
typedef __attribute__((ext_vector_type(4))) float f32x4;

#define NT 32
#define NB 64
#define NA 16
#define NF 128
#define DT 512
#define NH 8
#define NHD 64

__device__ __forceinline__ unsigned short f2b(float f) {
  union { float f; unsigned u; } c; c.f = f;
  unsigned r = c.u + 0x7fffu + ((c.u >> 16) & 1u);
  return (unsigned short)(r >> 16);
}
__device__ __forceinline__ float b2f(unsigned short u) {
  union { unsigned u; float f; } c; c.u = ((unsigned)u) << 16;
  return c.f;
}
__device__ __forceinline__ unsigned cvt2(float a, float b) {
  return (unsigned)f2b(a) | ((unsigned)f2b(b) << 16);
}

__device__ __forceinline__ void gload16(const void* g, void* l) {
  __builtin_amdgcn_global_load_lds(
      (const __attribute__((address_space(1))) void*)g,
      (__attribute__((address_space(3))) void*)l, 16, 0, 0);
}

#define BAR() asm volatile("s_barrier" ::: "memory")

// ---------------- f32 -> bf16 cast (weights only) ----------------
__global__ __launch_bounds__(256) void cast_kernel(const float* __restrict__ src,
                                                   unsigned short* __restrict__ dst) {
  long i = ((long)blockIdx.x * 256 + threadIdx.x) * 8;
  float4 v0 = *(const float4*)(src + i);
  float4 v1 = *(const float4*)(src + i + 4);
  uint4 o;
  o.x = cvt2(v0.x, v0.y);
  o.y = cvt2(v0.z, v0.w);
  o.z = cvt2(v1.x, v1.y);
  o.w = cvt2(v1.z, v1.w);
  *(uint4*)(dst + i) = o;
}

// =============== 128x256 GEMM, f32 A staged raw into LDS: C = A@B^T + bias ===============
// 512 threads = 8 waves (2M x 4N), per-wave 64x64 out (acc 4x4). BK=32, 16 K-tiles,
// 2 LDS slots (64 KB total -> 2 blocks/CU). r4-proven loop skeleton: stage-at-top,
// counted vmcnt(4), 2 barriers/group. A kept f32 in LDS (global_load_lds of raw bytes),
// converted to bf16 at frag-read time (2x ds_read_b128 + 4 pack-cvt per frag) -> no
// separate cast pass over ctx (536 MB read + 268 MB write saved).
// Swizzles (involutions, applied to global source + read addr; LDS dest stays linear):
//   A rows = 128 B (32 f32): 16B-chunk ^= (row&7)   [r4-proven profile, 0 conflicts]
//   B rows =  64 B (32 bf16): 16B-chunk ^= ((row>>1)&3)  [full 32-bank coverage per 8 rows]
// MODE 0 = KV (NCB=2: colTiles 0,1 -> K row-linear; 2,3 -> V row-permuted)
// MODE 1 = Q  (NCB=1: bf16 row-linear)
template <int MODE, int NCB>
__global__ __launch_bounds__(512, 4) void gemm_f32a(const float* __restrict__ A,
                                                    const unsigned short* __restrict__ Bg,
                                                    const float* __restrict__ bias0,
                                                    const float* __restrict__ bias1,
                                                    unsigned short* __restrict__ C0,
                                                    unsigned short* __restrict__ C1) {
  __shared__ __align__(16) float Asf[2][128 * 32];           // 16 KB / slot
  __shared__ __align__(16) unsigned short Bsb[2][256 * 32];  // 16 KB / slot
  const int tid = threadIdx.x;
  const int lane = tid & 63;
  const int l4 = lane & 15, lg = lane >> 4;
  const int w = tid >> 6;
  const int wm = w >> 2, wn = w & 3;

  // XCD-bijective swizzle (grid divisible by 8), colTile in low NCB bits
  const int nwg = gridDim.x;
  const int bid = blockIdx.x;
  const int swz = (bid & 7) * (nwg >> 3) + (bid >> 3);
  const long rowTile = swz >> NCB;
  const int colTile = swz & ((1 << NCB) - 1);

  // ---- staging geometry ----
  // A: 128 rows x 128 B; unit u (16B): row u>>3, chunk u&7. Thread: units tid, tid+512.
  const int sA = (tid & 7) ^ ((tid >> 3) & 7);  // source chunk (row&7 same for both units)
  const float* Agl = A + (rowTile * 128 + (tid >> 3)) * 512L + sA * 4;
  // B: 256 rows x 64 B; unit u: row u>>2, chunk u&3. Thread: units tid, tid+512.
  const int sB = (tid & 3) ^ ((tid >> 3) & 3);  // ((row>>1)&3) same for both units
  const unsigned short* Bgl = Bg + ((long)colTile * 256 + (tid >> 2)) * 512L + sB * 8;

  auto stage = [&](int s, int kc) {  // kc = T*32 (elems in each dtype)
    gload16(Agl + kc, &Asf[s][w * 256]);
    gload16(Agl + 64 * 512L + kc, &Asf[s][2048 + w * 256]);
    gload16(Bgl + kc, &Bsb[s][w * 512]);
    gload16(Bgl + 128 * 512L + kc, &Bsb[s][4096 + w * 512]);
  };

  const f32x4 zero = {0.f, 0.f, 0.f, 0.f};
  f32x4 acc[4][4];
#pragma unroll
  for (int i = 0; i < 4; i++)
#pragma unroll
    for (int j = 0; j < 4; j++) acc[i][j] = zero;

  // frag addressing constants (lane-invariant row&7 / (row>>1)&3 reductions)
  const int chA = (l4 & 7);        // A chunk xor term (row&7 == l4&7)
  const int chB = ((l4 >> 1) & 3); // B chunk xor term

  stage(0, 0);

#pragma unroll 1
  for (int T = 0; T < 16; T++) {
    const int s = T & 1;
    BAR();  // all waves done reading slot s^1
    if (T < 15) {
      stage(s ^ 1, (T + 1) * 32);
      asm volatile("s_waitcnt vmcnt(4)" ::: "memory");  // tile T's 4 loads done
    } else {
      asm volatile("s_waitcnt vmcnt(0)" ::: "memory");
    }
    BAR();  // tile T resident for all waves
    // ---- B frags (bf16 direct) ----
    short8 bf[4];
#pragma unroll
    for (int n = 0; n < 4; n++) {
      int rb = wn * 64 + n * 16 + l4;
      bf[n] = *(const short8*)&Bsb[s][rb * 32 + (lg ^ chB) * 8];
    }
    // ---- A frags (f32 -> bf16 pack) ----
    short8 af[4];
#pragma unroll
    for (int m = 0; m < 4; m++) {
      int ra = wm * 64 + m * 16 + l4;
      int c0 = (lg * 2) ^ chA;
      f32x4 p0 = *(const f32x4*)&Asf[s][ra * 32 + c0 * 4];
      f32x4 p1 = *(const f32x4*)&Asf[s][ra * 32 + (c0 ^ 1) * 4];
      union { unsigned u[4]; short8 s8; } cv;
      cv.u[0] = cvt2(p0[0], p0[1]);
      cv.u[1] = cvt2(p0[2], p0[3]);
      cv.u[2] = cvt2(p1[0], p1[1]);
      cv.u[3] = cvt2(p1[2], p1[3]);
      af[m] = cv.s8;
    }
    __builtin_amdgcn_s_setprio(1);
#pragma unroll
    for (int m = 0; m < 4; m++)
#pragma unroll
      for (int n = 0; n < 4; n++)
        acc[m][n] = __builtin_amdgcn_mfma_f32_16x16x32_bf16(af[m], bf[n], acc[m][n], 0, 0, 0);
    __builtin_amdgcn_s_setprio(0);
  }

  const long rowBase = rowTile * 128 + wm * 64;

  if constexpr (MODE == 0) {  // KV
    if (colTile < 2) {        // K: row-linear ((t,f,b) reshape is a memory no-op)
#pragma unroll
      for (int n = 0; n < 4; n++) {
        int gCol = colTile * 256 + wn * 64 + n * 16 + l4;
        float bs = bias0[gCol];
#pragma unroll
        for (int m = 0; m < 4; m++)
#pragma unroll
          for (int r = 0; r < 4; r++) {
            long gRow = rowBase + m * 16 + lg * 4 + r;
            C0[gRow * 512 + gCol] = f2b(acc[m][n][r] + bs);
          }
      }
    } else {  // V: row (fi*64+bi) -> (bi*128+fi) within each t
#pragma unroll
      for (int n = 0; n < 4; n++) {
        int gCol = (colTile - 2) * 256 + wn * 64 + n * 16 + l4;
        float bs = bias1[gCol];
#pragma unroll
        for (int m = 0; m < 4; m++)
#pragma unroll
          for (int r = 0; r < 4; r++) {
            long gRow = rowBase + m * 16 + lg * 4 + r;
            long rr = gRow & 8191;
            long vrow = (gRow - rr) + ((rr & 63) << 7) + (rr >> 6);
            C1[vrow * 512 + gCol] = f2b(acc[m][n][r] + bs);
          }
      }
    }
  } else {  // Q: bf16 row-linear
#pragma unroll
    for (int n = 0; n < 4; n++) {
      int gCol = colTile * 256 + wn * 64 + n * 16 + l4;
      float bs = bias0[gCol];
#pragma unroll
      for (int m = 0; m < 4; m++)
#pragma unroll
        for (int r = 0; r < 4; r++) {
          long gRow = rowBase + m * 16 + lg * 4 + r;
          C0[gRow * 512 + gCol] = f2b(acc[m][n][r] + bs);
        }
    }
  }
}

// ---------------- O projection (r7-proven): glds bf16 A/B, 128^2, f32 out ----------------
__global__ __launch_bounds__(256) void gemm_o(const unsigned short* __restrict__ A,
                                              const unsigned short* __restrict__ Bg,
                                              const float* __restrict__ bias0,
                                              float* __restrict__ C) {
  __shared__ __align__(16) unsigned short As[128 * 32];
  __shared__ __align__(16) unsigned short Bs[128 * 32];
  const int tid = threadIdx.x;
  const int lane = tid & 63;
  const int l4 = lane & 15, lg = lane >> 4;
  const int w = tid >> 6;
  const int wm = w >> 1, wn = w & 1;

  const int nwg = gridDim.x;
  const int bid = blockIdx.x;
  const int swz = (bid & 7) * (nwg >> 3) + (bid >> 3);
  const long rowTile = swz >> 2;
  const int colTile = swz & 3;

  const int srow = lane >> 2;
  const int scol = (lane & 3) * 8;
  const unsigned short* Ab = A + (rowTile * 128 + w * 16 + srow) * 512L + scol;
  const unsigned short* Ab2 = Ab + 64 * 512L;
  const unsigned short* Bb = Bg + ((long)colTile * 128 + w * 16 + srow) * 512L + scol;
  const unsigned short* Bb2 = Bb + 64 * 512L;
  unsigned short* lA = As + w * 512;
  unsigned short* lA2 = As + (w + 4) * 512;
  unsigned short* lB = Bs + w * 512;
  unsigned short* lB2 = Bs + (w + 4) * 512;

  const f32x4 zero = {0.f, 0.f, 0.f, 0.f};
  f32x4 acc[4][4];
#pragma unroll
  for (int i = 0; i < 4; i++)
#pragma unroll
    for (int j = 0; j < 4; j++) acc[i][j] = zero;

  for (int k0 = 0; k0 < 512; k0 += 32) {
    gload16(Ab + k0, lA);
    gload16(Ab2 + k0, lA2);
    gload16(Bb + k0, lB);
    gload16(Bb2 + k0, lB2);
    __syncthreads();
    short8 af[4], bfr[4];
#pragma unroll
    for (int i = 0; i < 4; i++)
      af[i] = *(const short8*)(As + (wm * 64 + i * 16 + l4) * 32 + lg * 8);
#pragma unroll
    for (int j = 0; j < 4; j++)
      bfr[j] = *(const short8*)(Bs + (wn * 64 + j * 16 + l4) * 32 + lg * 8);
#pragma unroll
    for (int i = 0; i < 4; i++)
#pragma unroll
      for (int j = 0; j < 4; j++)
        acc[i][j] = __builtin_amdgcn_mfma_f32_16x16x32_bf16(af[i], bfr[j], acc[i][j], 0, 0, 0);
    __syncthreads();
  }

  const long rowBase = rowTile * 128 + wm * 64;
#pragma unroll
  for (int j = 0; j < 4; j++) {
    int gCol = colTile * 128 + wn * 64 + j * 16 + l4;
    float bs = bias0[gCol];
#pragma unroll
    for (int i = 0; i < 4; i++)
#pragma unroll
      for (int r = 0; r < 4; r++) {
        long gRow = rowBase + i * 16 + lg * 4 + r;
        long tt = gRow >> 10;
        long bi = (gRow >> 4) & 63;
        long ai = gRow & 15;
        long orow = ((tt * 16 + ai) << 6) + bi;
        C[orow * 512 + gCol] = acc[i][j][r] + bs;
      }
  }
}

// ---------------- attention (r7-proven): one block per (t,b); 4 waves x 2 heads; MFMA PV ----------------
__global__ __launch_bounds__(256) void attn_kernel(const unsigned short* __restrict__ Kst,
                                                   const unsigned short* __restrict__ Vst,
                                                   const unsigned short* __restrict__ Qst,
                                                   const int* __restrict__ mask,
                                                   float* __restrict__ wout,
                                                   unsigned short* __restrict__ attn_out) {
  __shared__ __align__(16) unsigned short wt[4][16][136];
  __shared__ int msh[NF];
  const int tid = threadIdx.x;
  const int lane = tid & 63;
  const int l4 = lane & 15, lg = lane >> 4;
  const int w = tid >> 6;
  const int tb = blockIdx.x;
  const int b = tb & 63;
  if (tid < NF) msh[tid] = mask[b * NF + tid];
  __syncthreads();

  const unsigned short* Kbase = Kst + (long)tb * NF * DT;
  const unsigned short* Vbase = Vst + (long)tb * NF * DT;
  const unsigned short* Qbase = Qst + (long)tb * NA * DT;
  const f32x4 zero = {0.f, 0.f, 0.f, 0.f};

  for (int hh = 0; hh < 2; hh++) {
    const int h = w * 2 + hh;
    const int co = h * 64;
    f32x4 acc[8];
#pragma unroll
    for (int i = 0; i < 8; i++) acc[i] = zero;
#pragma unroll
    for (int ks = 0; ks < 2; ks++) {
      short8 qf = *(const short8*)(Qbase + (long)l4 * DT + co + ks * 32 + lg * 8);
#pragma unroll
      for (int m0 = 0; m0 < 8; m0++) {
        short8 kf = *(const short8*)(Kbase + (long)(m0 * 16 + l4) * DT + co + ks * 32 + lg * 8);
        acc[m0] = __builtin_amdgcn_mfma_f32_16x16x32_bf16(kf, qf, acc[m0], 0, 0, 0);
      }
    }
    float lv[8][4];
    float mx = -3.0e38f;
#pragma unroll
    for (int m0 = 0; m0 < 8; m0++)
#pragma unroll
      for (int r = 0; r < 4; r++) {
        int f = m0 * 16 + lg * 4 + r;
        float v = acc[m0][r] * 0.125f;
        if (msh[f] == 0) v = -1.0e9f;
        lv[m0][r] = v;
        mx = fmaxf(mx, v);
      }
    mx = fmaxf(mx, __shfl_xor(mx, 16, 64));
    mx = fmaxf(mx, __shfl_xor(mx, 32, 64));
    float s = 0.f;
#pragma unroll
    for (int m0 = 0; m0 < 8; m0++)
#pragma unroll
      for (int r = 0; r < 4; r++) {
        float p = __expf(lv[m0][r] - mx);
        lv[m0][r] = p;
        s += p;
      }
    s += __shfl_xor(s, 16, 64);
    s += __shfl_xor(s, 32, 64);
    float inv = 1.0f / s;
    float* wrow = wout + ((long)tb * NH + h) * (NF * NA);
#pragma unroll
    for (int m0 = 0; m0 < 8; m0++)
#pragma unroll
      for (int r = 0; r < 4; r++) {
        int f = m0 * 16 + lg * 4 + r;
        float wv = lv[m0][r] * inv;
        wrow[f * 16 + l4] = wv;
        wt[w][l4][f] = f2b(wv);
      }
    asm volatile("s_waitcnt lgkmcnt(0)" ::: "memory");
    __builtin_amdgcn_sched_barrier(0);
    f32x4 pacc[4];
#pragma unroll
    for (int m0 = 0; m0 < 4; m0++) pacc[m0] = zero;
#pragma unroll
    for (int ks = 0; ks < 4; ks++) {
      short8 wf = *(const short8*)&wt[w][l4][ks * 32 + lg * 8];
#pragma unroll
      for (int m0 = 0; m0 < 4; m0++) {
        short8 vf;
#pragma unroll
        for (int j = 0; j < 8; j++)
          vf[j] = (short)Vbase[(long)(ks * 32 + lg * 8 + j) * DT + co + m0 * 16 + l4];
        pacc[m0] = __builtin_amdgcn_mfma_f32_16x16x32_bf16(vf, wf, pacc[m0], 0, 0, 0);
      }
    }
#pragma unroll
    for (int m0 = 0; m0 < 4; m0++)
#pragma unroll
      for (int r = 0; r < 4; r++)
        attn_out[((long)tb * NA + l4) * DT + co + m0 * 16 + lg * 4 + r] = f2b(pacc[m0][r]);
  }
}

extern "C" void kernel_launch(void* const* d_in, const int* in_sizes, int n_in,
                              void* d_out, int out_size, void* d_ws, size_t ws_size,
                              hipStream_t stream) {
  const float* q_embeds = (const float*)d_in[0];
  const float* ctx = (const float*)d_in[1];
  const int* mask = (const int*)d_in[2];
  const float* Wq = (const float*)d_in[3];
  const float* bq = (const float*)d_in[4];
  const float* Wk = (const float*)d_in[5];
  const float* bk = (const float*)d_in[6];
  const float* Wv = (const float*)d_in[7];
  const float* bv = (const float*)d_in[8];
  const float* Wo = (const float*)d_in[9];
  const float* bo = (const float*)d_in[10];

  float* out0 = (float*)d_out;                   // (t,a,b,d) f32
  float* wout = out0 + (long)NT * NA * NB * DT;  // (t,b,H,f,a) f32

  const long W_ELEMS = 4L * 512 * 512;
  const long MQ = (long)NT * NB * NA;    // 32768
  const long MKV = (long)NT * NF * NB;   // 262144
  unsigned short* Wb = (unsigned short*)d_ws;
  unsigned short* Qst = Wb + W_ELEMS;
  unsigned short* Kst = Qst + MQ * DT;
  unsigned short* Vst = Kst + MKV * DT;
  unsigned short* attnst = Vst + MKV * DT;
  size_t needed = (size_t)(W_ELEMS + 2 * MQ * DT + 2 * MKV * DT) * 2;
  if (ws_size < needed) return;

  cast_kernel<<<128, 256, 0, stream>>>(Wq, Wb);
  cast_kernel<<<128, 256, 0, stream>>>(Wk, Wb + 512 * 512);
  cast_kernel<<<128, 256, 0, stream>>>(Wv, Wb + 2 * 512 * 512);
  cast_kernel<<<128, 256, 0, stream>>>(Wo, Wb + 3 * 512 * 512);

  // Q projection: f32 A direct (no prepass). grid = 256 rowTiles x 2 colTiles
  gemm_f32a<1, 1><<<(unsigned)(MQ / 128 * 2), 512, 0, stream>>>(
      q_embeds, Wb, bq, nullptr, Qst, nullptr);

  // K+V projection: f32 ctx direct (no cast pass). grid = 2048 rowTiles x 4 colTiles
  gemm_f32a<0, 2><<<(unsigned)(MKV / 128 * 4), 512, 0, stream>>>(
      ctx, Wb + 512 * 512, bk, bv, Kst, Vst);

  attn_kernel<<<NT * NB, 256, 0, stream>>>(Kst, Vst, Qst, mask, wout, attnst);

  gemm_o<<<(unsigned)(MQ / 128 * 4), 256, 0, stream>>>(attnst, Wb + 3 * 512 * 512, bo, out0);
}

// Round 9
// 796.480 us; speedup vs baseline: 1.4782x; 1.0224x over previous
//
#include <hip/hip_runtime.h>
#include <hip/hip_bf16.h>

typedef __attribute__((ext_vector_type(8))) short short8;
typedef __attribute__((ext_vector_type(4))) float f32x4;

#define NT 32
#define NB 64
#define NA 16
#define NF 128
#define DT 512
#define NH 8
#define NHD 64

// f32 -> bf16 RNE via compiler intrinsic (emits v_cvt_pk_bf16_f32 when paired — m240)
__device__ __forceinline__ unsigned short f2b(float f) {
  return __bfloat16_as_ushort(__float2bfloat16(f));
}
__device__ __forceinline__ float b2f(unsigned short u) {
  union { unsigned u; float f; } c; c.u = ((unsigned)u) << 16;
  return c.f;
}
__device__ __forceinline__ unsigned cvt2(float a, float b) {
  return (unsigned)f2b(a) | ((unsigned)f2b(b) << 16);
}

__device__ __forceinline__ void gload16(const void* g, void* l) {
  __builtin_amdgcn_global_load_lds(
      (const __attribute__((address_space(1))) void*)g,
      (__attribute__((address_space(3))) void*)l, 16, 0, 0);
}

#define BAR() asm volatile("s_barrier" ::: "memory")

// ---------------- f32 -> bf16 cast (weights only) ----------------
__global__ __launch_bounds__(256) void cast_kernel(const float* __restrict__ src,
                                                   unsigned short* __restrict__ dst) {
  long i = ((long)blockIdx.x * 256 + threadIdx.x) * 8;
  float4 v0 = *(const float4*)(src + i);
  float4 v1 = *(const float4*)(src + i + 4);
  uint4 o;
  o.x = cvt2(v0.x, v0.y);
  o.y = cvt2(v0.z, v0.w);
  o.z = cvt2(v1.x, v1.y);
  o.w = cvt2(v1.z, v1.w);
  *(uint4*)(dst + i) = o;
}

// =============== 128x256 GEMM, f32 A staged raw into LDS: C = A@B^T + bias ===============
// (r8 structure, proven: 814 us total) — only the f32->bf16 conversions changed to
// compiler-fusable v_cvt_pk_bf16_f32 form (was manual bit-twiddle, ~8 VALU/pair).
// 512 threads = 8 waves (2M x 4N), per-wave 64x64 out (acc 4x4). BK=32, 16 K-tiles,
// 2 LDS slots (64 KB total -> 2 blocks/CU). Stage-at-top, counted vmcnt(4), 2 barriers.
// A kept f32 in LDS (global_load_lds raw); cvt at frag-read time. Swizzles unchanged.
// MODE 0 = KV (NCB=2); MODE 1 = Q (NCB=1)
template <int MODE, int NCB>
__global__ __launch_bounds__(512, 4) void gemm_f32a(const float* __restrict__ A,
                                                    const unsigned short* __restrict__ Bg,
                                                    const float* __restrict__ bias0,
                                                    const float* __restrict__ bias1,
                                                    unsigned short* __restrict__ C0,
                                                    unsigned short* __restrict__ C1) {
  __shared__ __align__(16) float Asf[2][128 * 32];           // 16 KB / slot
  __shared__ __align__(16) unsigned short Bsb[2][256 * 32];  // 16 KB / slot
  const int tid = threadIdx.x;
  const int lane = tid & 63;
  const int l4 = lane & 15, lg = lane >> 4;
  const int w = tid >> 6;
  const int wm = w >> 2, wn = w & 3;

  const int nwg = gridDim.x;
  const int bid = blockIdx.x;
  const int swz = (bid & 7) * (nwg >> 3) + (bid >> 3);
  const long rowTile = swz >> NCB;
  const int colTile = swz & ((1 << NCB) - 1);

  const int sA = (tid & 7) ^ ((tid >> 3) & 7);
  const float* Agl = A + (rowTile * 128 + (tid >> 3)) * 512L + sA * 4;
  const int sB = (tid & 3) ^ ((tid >> 3) & 3);
  const unsigned short* Bgl = Bg + ((long)colTile * 256 + (tid >> 2)) * 512L + sB * 8;

  auto stage = [&](int s, int kc) {
    gload16(Agl + kc, &Asf[s][w * 256]);
    gload16(Agl + 64 * 512L + kc, &Asf[s][2048 + w * 256]);
    gload16(Bgl + kc, &Bsb[s][w * 512]);
    gload16(Bgl + 128 * 512L + kc, &Bsb[s][4096 + w * 512]);
  };

  const f32x4 zero = {0.f, 0.f, 0.f, 0.f};
  f32x4 acc[4][4];
#pragma unroll
  for (int i = 0; i < 4; i++)
#pragma unroll
    for (int j = 0; j < 4; j++) acc[i][j] = zero;

  const int chA = (l4 & 7);
  const int chB = ((l4 >> 1) & 3);

  stage(0, 0);

#pragma unroll 1
  for (int T = 0; T < 16; T++) {
    const int s = T & 1;
    BAR();
    if (T < 15) {
      stage(s ^ 1, (T + 1) * 32);
      asm volatile("s_waitcnt vmcnt(4)" ::: "memory");
    } else {
      asm volatile("s_waitcnt vmcnt(0)" ::: "memory");
    }
    BAR();
    short8 bf[4];
#pragma unroll
    for (int n = 0; n < 4; n++) {
      int rb = wn * 64 + n * 16 + l4;
      bf[n] = *(const short8*)&Bsb[s][rb * 32 + (lg ^ chB) * 8];
    }
    short8 af[4];
#pragma unroll
    for (int m = 0; m < 4; m++) {
      int ra = wm * 64 + m * 16 + l4;
      int c0 = (lg * 2) ^ chA;
      f32x4 p0 = *(const f32x4*)&Asf[s][ra * 32 + c0 * 4];
      f32x4 p1 = *(const f32x4*)&Asf[s][ra * 32 + (c0 ^ 1) * 4];
      union { unsigned u[4]; short8 s8; } cv;
      cv.u[0] = cvt2(p0[0], p0[1]);
      cv.u[1] = cvt2(p0[2], p0[3]);
      cv.u[2] = cvt2(p1[0], p1[1]);
      cv.u[3] = cvt2(p1[2], p1[3]);
      af[m] = cv.s8;
    }
    __builtin_amdgcn_s_setprio(1);
#pragma unroll
    for (int m = 0; m < 4; m++)
#pragma unroll
      for (int n = 0; n < 4; n++)
        acc[m][n] = __builtin_amdgcn_mfma_f32_16x16x32_bf16(af[m], bf[n], acc[m][n], 0, 0, 0);
    __builtin_amdgcn_s_setprio(0);
  }

  const long rowBase = rowTile * 128 + wm * 64;

  if constexpr (MODE == 0) {  // KV
    if (colTile < 2) {        // K: row-linear ((t,f,b) reshape is a memory no-op)
#pragma unroll
      for (int n = 0; n < 4; n++) {
        int gCol = colTile * 256 + wn * 64 + n * 16 + l4;
        float bs = bias0[gCol];
#pragma unroll
        for (int m = 0; m < 4; m++)
#pragma unroll
          for (int r = 0; r < 4; r++) {
            long gRow = rowBase + m * 16 + lg * 4 + r;
            C0[gRow * 512 + gCol] = f2b(acc[m][n][r] + bs);
          }
      }
    } else {  // V: row (fi*64+bi) -> (bi*128+fi) within each t
#pragma unroll
      for (int n = 0; n < 4; n++) {
        int gCol = (colTile - 2) * 256 + wn * 64 + n * 16 + l4;
        float bs = bias1[gCol];
#pragma unroll
        for (int m = 0; m < 4; m++)
#pragma unroll
          for (int r = 0; r < 4; r++) {
            long gRow = rowBase + m * 16 + lg * 4 + r;
            long rr = gRow & 8191;
            long vrow = (gRow - rr) + ((rr & 63) << 7) + (rr >> 6);
            C1[vrow * 512 + gCol] = f2b(acc[m][n][r] + bs);
          }
      }
    }
  } else {  // Q: bf16 row-linear
#pragma unroll
    for (int n = 0; n < 4; n++) {
      int gCol = colTile * 256 + wn * 64 + n * 16 + l4;
      float bs = bias0[gCol];
#pragma unroll
      for (int m = 0; m < 4; m++)
#pragma unroll
        for (int r = 0; r < 4; r++) {
          long gRow = rowBase + m * 16 + lg * 4 + r;
          C0[gRow * 512 + gCol] = f2b(acc[m][n][r] + bs);
        }
    }
  }
}

// ---------------- O projection (r7-proven): glds bf16 A/B, 128^2, f32 out ----------------
__global__ __launch_bounds__(256) void gemm_o(const unsigned short* __restrict__ A,
                                              const unsigned short* __restrict__ Bg,
                                              const float* __restrict__ bias0,
                                              float* __restrict__ C) {
  __shared__ __align__(16) unsigned short As[128 * 32];
  __shared__ __align__(16) unsigned short Bs[128 * 32];
  const int tid = threadIdx.x;
  const int lane = tid & 63;
  const int l4 = lane & 15, lg = lane >> 4;
  const int w = tid >> 6;
  const int wm = w >> 1, wn = w & 1;

  const int nwg = gridDim.x;
  const int bid = blockIdx.x;
  const int swz = (bid & 7) * (nwg >> 3) + (bid >> 3);
  const long rowTile = swz >> 2;
  const int colTile = swz & 3;

  const int srow = lane >> 2;
  const int scol = (lane & 3) * 8;
  const unsigned short* Ab = A + (rowTile * 128 + w * 16 + srow) * 512L + scol;
  const unsigned short* Ab2 = Ab + 64 * 512L;
  const unsigned short* Bb = Bg + ((long)colTile * 128 + w * 16 + srow) * 512L + scol;
  const unsigned short* Bb2 = Bb + 64 * 512L;
  unsigned short* lA = As + w * 512;
  unsigned short* lA2 = As + (w + 4) * 512;
  unsigned short* lB = Bs + w * 512;
  unsigned short* lB2 = Bs + (w + 4) * 512;

  const f32x4 zero = {0.f, 0.f, 0.f, 0.f};
  f32x4 acc[4][4];
#pragma unroll
  for (int i = 0; i < 4; i++)
#pragma unroll
    for (int j = 0; j < 4; j++) acc[i][j] = zero;

  for (int k0 = 0; k0 < 512; k0 += 32) {
    gload16(Ab + k0, lA);
    gload16(Ab2 + k0, lA2);
    gload16(Bb + k0, lB);
    gload16(Bb2 + k0, lB2);
    __syncthreads();
    short8 af[4], bfr[4];
#pragma unroll
    for (int i = 0; i < 4; i++)
      af[i] = *(const short8*)(As + (wm * 64 + i * 16 + l4) * 32 + lg * 8);
#pragma unroll
    for (int j = 0; j < 4; j++)
      bfr[j] = *(const short8*)(Bs + (wn * 64 + j * 16 + l4) * 32 + lg * 8);
#pragma unroll
    for (int i = 0; i < 4; i++)
#pragma unroll
      for (int j = 0; j < 4; j++)
        acc[i][j] = __builtin_amdgcn_mfma_f32_16x16x32_bf16(af[i], bfr[j], acc[i][j], 0, 0, 0);
    __syncthreads();
  }

  const long rowBase = rowTile * 128 + wm * 64;
#pragma unroll
  for (int j = 0; j < 4; j++) {
    int gCol = colTile * 128 + wn * 64 + j * 16 + l4;
    float bs = bias0[gCol];
#pragma unroll
    for (int i = 0; i < 4; i++)
#pragma unroll
      for (int r = 0; r < 4; r++) {
        long gRow = rowBase + i * 16 + lg * 4 + r;
        long tt = gRow >> 10;
        long bi = (gRow >> 4) & 63;
        long ai = gRow & 15;
        long orow = ((tt * 16 + ai) << 6) + bi;
        C[orow * 512 + gCol] = acc[i][j][r] + bs;
      }
  }
}

// ---------------- attention (r7-proven): one block per (t,b); 4 waves x 2 heads; MFMA PV ----------------
__global__ __launch_bounds__(256) void attn_kernel(const unsigned short* __restrict__ Kst,
                                                   const unsigned short* __restrict__ Vst,
                                                   const unsigned short* __restrict__ Qst,
                                                   const int* __restrict__ mask,
                                                   float* __restrict__ wout,
                                                   unsigned short* __restrict__ attn_out) {
  __shared__ __align__(16) unsigned short wt[4][16][136];
  __shared__ int msh[NF];
  const int tid = threadIdx.x;
  const int lane = tid & 63;
  const int l4 = lane & 15, lg = lane >> 4;
  const int w = tid >> 6;
  const int tb = blockIdx.x;
  const int b = tb & 63;
  if (tid < NF) msh[tid] = mask[b * NF + tid];
  __syncthreads();

  const unsigned short* Kbase = Kst + (long)tb * NF * DT;
  const unsigned short* Vbase = Vst + (long)tb * NF * DT;
  const unsigned short* Qbase = Qst + (long)tb * NA * DT;
  const f32x4 zero = {0.f, 0.f, 0.f, 0.f};

  for (int hh = 0; hh < 2; hh++) {
    const int h = w * 2 + hh;
    const int co = h * 64;
    f32x4 acc[8];
#pragma unroll
    for (int i = 0; i < 8; i++) acc[i] = zero;
#pragma unroll
    for (int ks = 0; ks < 2; ks++) {
      short8 qf = *(const short8*)(Qbase + (long)l4 * DT + co + ks * 32 + lg * 8);
#pragma unroll
      for (int m0 = 0; m0 < 8; m0++) {
        short8 kf = *(const short8*)(Kbase + (long)(m0 * 16 + l4) * DT + co + ks * 32 + lg * 8);
        acc[m0] = __builtin_amdgcn_mfma_f32_16x16x32_bf16(kf, qf, acc[m0], 0, 0, 0);
      }
    }
    float lv[8][4];
    float mx = -3.0e38f;
#pragma unroll
    for (int m0 = 0; m0 < 8; m0++)
#pragma unroll
      for (int r = 0; r < 4; r++) {
        int f = m0 * 16 + lg * 4 + r;
        float v = acc[m0][r] * 0.125f;
        if (msh[f] == 0) v = -1.0e9f;
        lv[m0][r] = v;
        mx = fmaxf(mx, v);
      }
    mx = fmaxf(mx, __shfl_xor(mx, 16, 64));
    mx = fmaxf(mx, __shfl_xor(mx, 32, 64));
    float s = 0.f;
#pragma unroll
    for (int m0 = 0; m0 < 8; m0++)
#pragma unroll
      for (int r = 0; r < 4; r++) {
        float p = __expf(lv[m0][r] - mx);
        lv[m0][r] = p;
        s += p;
      }
    s += __shfl_xor(s, 16, 64);
    s += __shfl_xor(s, 32, 64);
    float inv = 1.0f / s;
    float* wrow = wout + ((long)tb * NH + h) * (NF * NA);
#pragma unroll
    for (int m0 = 0; m0 < 8; m0++)
#pragma unroll
      for (int r = 0; r < 4; r++) {
        int f = m0 * 16 + lg * 4 + r;
        float wv = lv[m0][r] * inv;
        wrow[f * 16 + l4] = wv;
        wt[w][l4][f] = f2b(wv);
      }
    asm volatile("s_waitcnt lgkmcnt(0)" ::: "memory");
    __builtin_amdgcn_sched_barrier(0);
    f32x4 pacc[4];
#pragma unroll
    for (int m0 = 0; m0 < 4; m0++) pacc[m0] = zero;
#pragma unroll
    for (int ks = 0; ks < 4; ks++) {
      short8 wf = *(const short8*)&wt[w][l4][ks * 32 + lg * 8];
#pragma unroll
      for (int m0 = 0; m0 < 4; m0++) {
        short8 vf;
#pragma unroll
        for (int j = 0; j < 8; j++)
          vf[j] = (short)Vbase[(long)(ks * 32 + lg * 8 + j) * DT + co + m0 * 16 + l4];
        pacc[m0] = __builtin_amdgcn_mfma_f32_16x16x32_bf16(vf, wf, pacc[m0], 0, 0, 0);
      }
    }
#pragma unroll
    for (int m0 = 0; m0 < 4; m0++)
#pragma unroll
      for (int r = 0; r < 4; r++)
        attn_out[((long)tb * NA + l4) * DT + co + m0 * 16 + lg * 4 + r] = f2b(pacc[m0][r]);
  }
}

extern "C" void kernel_launch(void* const* d_in, const int* in_sizes, int n_in,
                              void* d_out, int out_size, void* d_ws, size_t ws_size,
                              hipStream_t stream) {
  const float* q_embeds = (const float*)d_in[0];
  const float* ctx = (const float*)d_in[1];
  const int* mask = (const int*)d_in[2];
  const float* Wq = (const float*)d_in[3];
  const float* bq = (const float*)d_in[4];
  const float* Wk = (const float*)d_in[5];
  const float* bk = (const float*)d_in[6];
  const float* Wv = (const float*)d_in[7];
  const float* bv = (const float*)d_in[8];
  const float* Wo = (const float*)d_in[9];
  const float* bo = (const float*)d_in[10];

  float* out0 = (float*)d_out;                   // (t,a,b,d) f32
  float* wout = out0 + (long)NT * NA * NB * DT;  // (t,b,H,f,a) f32

  const long W_ELEMS = 4L * 512 * 512;
  const long MQ = (long)NT * NB * NA;    // 32768
  const long MKV = (long)NT * NF * NB;   // 262144
  unsigned short* Wb = (unsigned short*)d_ws;
  unsigned short* Qst = Wb + W_ELEMS;
  unsigned short* Kst = Qst + MQ * DT;
  unsigned short* Vst = Kst + MKV * DT;
  unsigned short* attnst = Vst + MKV * DT;
  size_t needed = (size_t)(W_ELEMS + 2 * MQ * DT + 2 * MKV * DT) * 2;
  if (ws_size < needed) return;

  cast_kernel<<<128, 256, 0, stream>>>(Wq, Wb);
  cast_kernel<<<128, 256, 0, stream>>>(Wk, Wb + 512 * 512);
  cast_kernel<<<128, 256, 0, stream>>>(Wv, Wb + 2 * 512 * 512);
  cast_kernel<<<128, 256, 0, stream>>>(Wo, Wb + 3 * 512 * 512);

  // Q projection: f32 A direct (no prepass)
  gemm_f32a<1, 1><<<(unsigned)(MQ / 128 * 2), 512, 0, stream>>>(
      q_embeds, Wb, bq, nullptr, Qst, nullptr);

  // K+V projection: f32 ctx direct (no cast pass)
  gemm_f32a<0, 2><<<(unsigned)(MKV / 128 * 4), 512, 0, stream>>>(
      ctx, Wb + 512 * 512, bk, bv, Kst, Vst);

  attn_kernel<<<NT * NB, 256, 0, stream>>>(Kst, Vst, Qst, mask, wout, attnst);

  gemm_o<<<(unsigned)(MQ / 128 * 4), 256, 0, stream>>>(attnst, Wb + 3 * 512 * 512, bo, out0);
}